// Round 10
// baseline (269.416 us; speedup 1.0000x reference)
//
#include <hip/hip_runtime.h>
#include <hip/hip_bf16.h>
#include <hip/hip_cooperative_groups.h>

namespace cg = cooperative_groups;

#define B_ 2
#define N_ 2048
#define FIN 512
#define H_ 8
#define DH 64
#define HD 512 /* H_*DH */
#define SLOPE 0.2f
#define NCHUNK 128
#define CH 16
#define NBLK 256
#define NTHR 512

typedef __attribute__((ext_vector_type(8))) short short8;
typedef __attribute__((ext_vector_type(4))) float f32x4;
typedef unsigned short ushort_t;

#define GLOAD_LDS(gp, lp)                                                   \
  __builtin_amdgcn_global_load_lds(                                         \
      (const __attribute__((address_space(1))) void*)(gp),                  \
      (__attribute__((address_space(3))) void*)(lp), 16, 0, 0)

// LDS union across phases: max member (gemm) = 98KB < 160KB -> 1 block/CU,
// 256 blocks co-resident => cooperative grid is safe.
union SMem {
  struct { float T[64][65]; } cvt;
  struct {
    ushort_t lA[2][2][128 * 64];  // 64KB
    ushort_t lB[2][2][64 * 64];   // 32KB
    float slp[2][128], srp[2][128];
  } gemm;
  struct {
    int hist[N_], sbase[N_], cursor[N_];
    float tsv[N_];
    int tsi[N_];
    float sval[N_];
    float redmn[8], redmx[8];
    int wtot[8], wexc[8];
  } sort;
};

__global__ __launch_bounds__(NTHR, 2) void k_mega(const float* f,
                                                  const float* W,
                                                  const float* aw, float* ws,
                                                  float* out) {
  __shared__ SMem sm;
  const int bid = blockIdx.x;
  const int tid = threadIdx.x;
  const int lane = tid & 63;
  const int wave = tid >> 6;

  // workspace layout (same as R9)
  float* g = ws;
  float* sl = g + B_ * N_ * HD;
  float* sr = sl + 32768;
  float* sv = sr + 32768;
  int* si = (int*)(sv + 32768);
  float* P1 = (float*)(si + 32768);
  float* P2 = P1 + 2097152;
  float* Zpe1 = P2 + 2097152;
  float* Zpe2 = Zpe1 + 32768;
  float* U1 = Zpe2 + 32768;
  float* U2 = U1 + 16 * 129 * 64;
  float* Zb1 = U2 + 16 * 129 * 64;
  float* Zb2 = Zb1 + 16 * 129;
  float* C1 = Zb2 + 16 * 129;
  float* C2 = C1 + 16 * NCHUNK * 64;
  float* Zc1 = C2 + 16 * NCHUNK * 64;
  float* Zc2 = Zc1 + 16 * NCHUNK;
  int* parr = (int*)(Zc2 + 16 * NCHUNK);
  ushort_t* fh = (ushort_t*)P1;  // aliases P1 (dead until chunks phase)
  ushort_t* fl = fh + 4096 * FIN;
  ushort_t* Bth = (ushort_t*)P2;  // aliases P2
  ushort_t* Btl = Bth + HD * FIN;

  cg::grid_group grid = cg::this_grid();

  // ================= phase 0: convert (f split + W transpose-split) ======
  if (bid < 64) {
    const int k0 = (bid & 7) * 64;
    const int n0 = (bid >> 3) * 64;
    const int tx = tid & 63, ty = tid >> 6;
#pragma unroll
    for (int p = 0; p < 8; ++p) {
      const int kr = p * 8 + ty;
      sm.cvt.T[kr][tx] = W[(k0 + kr) * HD + n0 + tx];
    }
    __syncthreads();
#pragma unroll
    for (int p = 0; p < 8; ++p) {
      const int nr = p * 8 + ty;
      const float x = sm.cvt.T[tx][nr];
      const __hip_bfloat16 hb = __float2bfloat16(x);
      const float hf = __bfloat162float(hb);
      const __hip_bfloat16 lb = __float2bfloat16(x - hf);
      Bth[(n0 + nr) * FIN + k0 + tx] = *(const ushort_t*)&hb;
      Btl[(n0 + nr) * FIN + k0 + tx] = *(const ushort_t*)&lb;
    }
  }
#pragma unroll
  for (int k = 0; k < 4; ++k) {
    const int i = (bid * NTHR + tid + k * (NBLK * NTHR)) * 4;
    const float4 v = *(const float4*)(f + i);
    const float vv[4] = {v.x, v.y, v.z, v.w};
    ushort_t hh[4], ll[4];
#pragma unroll
    for (int j = 0; j < 4; ++j) {
      const float x = vv[j];
      const __hip_bfloat16 hb = __float2bfloat16(x);
      const float hf = __bfloat162float(hb);
      const __hip_bfloat16 lb = __float2bfloat16(x - hf);
      hh[j] = *(const ushort_t*)&hb;
      ll[j] = *(const ushort_t*)&lb;
    }
    ushort4 ho, lo;
    ho.x = hh[0]; ho.y = hh[1]; ho.z = hh[2]; ho.w = hh[3];
    lo.x = ll[0]; lo.y = ll[1]; lo.z = ll[2]; lo.w = ll[3];
    *(ushort4*)(fh + i) = ho;
    *(ushort4*)(fl + i) = lo;
  }
  grid.sync();

  // ================= phase 1: GEMM + fused sl/sr ==========================
  {
    const int row0 = (bid & 31) * 128;
    const int gy = bid >> 5;
    const int col0 = gy * 64;
    const int wm = (wave >> 1) * 32;
    const int wn = (wave & 1) * 32;
    f32x4 acc[2][2] = {};

#define STAGE(buf, k0)                                                      \
  {                                                                         \
    _Pragma("unroll") for (int p = 0; p < 2; ++p) {                         \
      const int q = p * 512 + tid;                                          \
      const int r = q >> 3, s = q & 7;                                      \
      const int gk = (k0) + ((s ^ (r & 7)) << 3);                           \
      GLOAD_LDS(fh + (row0 + r) * FIN + gk, &sm.gemm.lA[buf][0][q * 8]);    \
      GLOAD_LDS(fl + (row0 + r) * FIN + gk, &sm.gemm.lA[buf][1][q * 8]);    \
    }                                                                       \
    {                                                                       \
      const int q = tid;                                                    \
      const int r = q >> 3, s = q & 7;                                      \
      const int gk = (k0) + ((s ^ (r & 7)) << 3);                           \
      GLOAD_LDS(Bth + (col0 + r) * FIN + gk, &sm.gemm.lB[buf][0][q * 8]);   \
      GLOAD_LDS(Btl + (col0 + r) * FIN + gk, &sm.gemm.lB[buf][1][q * 8]);   \
    }                                                                       \
  }

    STAGE(0, 0);
    __syncthreads();
    int cur = 0;
    for (int t = 0; t < 8; ++t) {
      if (t + 1 < 8) STAGE(cur ^ 1, (t + 1) * 64);
#pragma unroll
      for (int kk = 0; kk < 2; ++kk) {
        short8 a_h[2], a_l[2], b_h[2], b_l[2];
        const int kbyte = kk * 64 + ((lane >> 4) << 4);
#pragma unroll
        for (int fm = 0; fm < 2; ++fm) {
          const int row = wm + fm * 16 + (lane & 15);
          const int off = (row * 128 + (kbyte ^ ((row & 7) << 4))) >> 1;
          a_h[fm] = *(const short8*)&sm.gemm.lA[cur][0][off];
          a_l[fm] = *(const short8*)&sm.gemm.lA[cur][1][off];
        }
#pragma unroll
        for (int fn = 0; fn < 2; ++fn) {
          const int nn = wn + fn * 16 + (lane & 15);
          const int off = (nn * 128 + (kbyte ^ ((nn & 7) << 4))) >> 1;
          b_h[fn] = *(const short8*)&sm.gemm.lB[cur][0][off];
          b_l[fn] = *(const short8*)&sm.gemm.lB[cur][1][off];
        }
#pragma unroll
        for (int fm = 0; fm < 2; ++fm)
#pragma unroll
          for (int fn = 0; fn < 2; ++fn) {
            acc[fm][fn] = __builtin_amdgcn_mfma_f32_16x16x32_bf16(
                a_h[fm], b_h[fn], acc[fm][fn], 0, 0, 0);
            acc[fm][fn] = __builtin_amdgcn_mfma_f32_16x16x32_bf16(
                a_h[fm], b_l[fn], acc[fm][fn], 0, 0, 0);
            acc[fm][fn] = __builtin_amdgcn_mfma_f32_16x16x32_bf16(
                a_l[fm], b_h[fn], acc[fm][fn], 0, 0, 0);
          }
      }
      __syncthreads();
      cur ^= 1;
    }
#undef STAGE

#pragma unroll
    for (int fm = 0; fm < 2; ++fm)
#pragma unroll
      for (int fn = 0; fn < 2; ++fn)
#pragma unroll
        for (int r = 0; r < 4; ++r) {
          const int row = row0 + wm + fm * 16 + ((lane >> 4) << 2) + r;
          const int col = col0 + wn + fn * 16 + (lane & 15);
          g[row * HD + col] = acc[fm][fn][r];
        }

    const float al0 = aw[wn + (lane & 15)];
    const float al1 = aw[wn + 16 + (lane & 15)];
    const float ar0 = aw[DH + wn + (lane & 15)];
    const float ar1 = aw[DH + wn + 16 + (lane & 15)];
#pragma unroll
    for (int fm = 0; fm < 2; ++fm)
#pragma unroll
      for (int r = 0; r < 4; ++r) {
        float vsl = acc[fm][0][r] * al0 + acc[fm][1][r] * al1;
        float vsr = acc[fm][0][r] * ar0 + acc[fm][1][r] * ar1;
#pragma unroll
        for (int off = 1; off < 16; off <<= 1) {
          vsl += __shfl_xor(vsl, off, 64);
          vsr += __shfl_xor(vsr, off, 64);
        }
        if ((lane & 15) == 0) {
          const int rr = wm + fm * 16 + ((lane >> 4) << 2) + r;
          sm.gemm.slp[wn >> 5][rr] = vsl;
          sm.gemm.srp[wn >> 5][rr] = vsr;
        }
      }
    __syncthreads();
    if (tid < 128) {
      const int grow = row0 + tid;
      const int b = grow >> 11, n = grow & (N_ - 1);
      sl[(b * H_ + gy) * N_ + n] = sm.gemm.slp[0][tid] + sm.gemm.slp[1][tid];
      sr[(b * H_ + gy) * N_ + n] = sm.gemm.srp[0][tid] + sm.gemm.srp[1][tid];
    }
  }
  grid.sync();

  // ================= phase 2: counting sort + split (bid<16) ==============
  if (bid < 16) {
    const int base = bid * N_;
    float v[4];
    int id[4];
#pragma unroll
    for (int e = 0; e < 4; ++e) {
      id[e] = tid + e * NTHR;
      v[e] = sr[base + id[e]];
    }
#pragma unroll
    for (int e = 0; e < 4; ++e) sm.sort.hist[tid + e * NTHR] = 0;
    float mn = fminf(fminf(v[0], v[1]), fminf(v[2], v[3]));
    float mx = fmaxf(fmaxf(v[0], v[1]), fmaxf(v[2], v[3]));
#pragma unroll
    for (int off = 32; off > 0; off >>= 1) {
      mn = fminf(mn, __shfl_xor(mn, off, 64));
      mx = fmaxf(mx, __shfl_xor(mx, off, 64));
    }
    if (lane == 0) { sm.sort.redmn[wave] = mn; sm.sort.redmx[wave] = mx; }
    __syncthreads();
    if (tid == 0) {
      float m1 = sm.sort.redmn[0], m2 = sm.sort.redmx[0];
#pragma unroll
      for (int w = 1; w < 8; ++w) {
        m1 = fminf(m1, sm.sort.redmn[w]);
        m2 = fmaxf(m2, sm.sort.redmx[w]);
      }
      sm.sort.redmn[0] = m1; sm.sort.redmx[0] = m2;
    }
    __syncthreads();
    const float vmin = sm.sort.redmn[0];
    const float range = sm.sort.redmx[0] - vmin;
    const float scalef = range > 0.f ? 2047.0f / range : 0.0f;
#define BUCKET(x)                                                            \
  ({ int b_ = (int)(((x) - vmin) * scalef); b_ > 2047 ? 2047 : b_; })
#pragma unroll
    for (int e = 0; e < 4; ++e) atomicAdd(&sm.sort.hist[BUCKET(v[e])], 1);
    __syncthreads();
    // exclusive scan: thread owns buckets [tid*4, tid*4+4)
    int h4[4], ssum = 0;
#pragma unroll
    for (int e = 0; e < 4; ++e) { h4[e] = sm.sort.hist[tid * 4 + e]; ssum += h4[e]; }
    int sc = ssum;
#pragma unroll
    for (int off = 1; off < 64; off <<= 1) {
      const int o = __shfl_up(sc, off, 64);
      if (lane >= off) sc += o;
    }
    if (lane == 63) sm.sort.wtot[wave] = sc;
    __syncthreads();
    if (tid == 0) {
      int r = 0;
#pragma unroll
      for (int w = 0; w < 8; ++w) { sm.sort.wexc[w] = r; r += sm.sort.wtot[w]; }
    }
    __syncthreads();
    int runb = sm.sort.wexc[wave] + (sc - ssum);
#pragma unroll
    for (int e = 0; e < 4; ++e) {
      sm.sort.sbase[tid * 4 + e] = runb;
      sm.sort.cursor[tid * 4 + e] = runb;
      runb += h4[e];
    }
    __syncthreads();
#pragma unroll
    for (int e = 0; e < 4; ++e) {
      const int b_ = BUCKET(v[e]);
      const int p = atomicAdd(&sm.sort.cursor[b_], 1);
      sm.sort.tsv[p] = v[e];
      sm.sort.tsi[p] = id[e];
    }
    __syncthreads();
#pragma unroll
    for (int e = 0; e < 4; ++e) {
      const int s = tid + e * NTHR;
      const float vx = sm.sort.tsv[s];
      const int ix = sm.sort.tsi[s];
      const int b_ = BUCKET(vx);
      const int lo = sm.sort.sbase[b_];
      const int cnt = sm.sort.hist[b_];
      int r = 0;
      for (int t2 = lo; t2 < lo + cnt; ++t2) {
        const float vt = sm.sort.tsv[t2];
        r += (vt < vx || (vt == vx && sm.sort.tsi[t2] < ix)) ? 1 : 0;
      }
      const int pos = lo + r;
      sv[base + pos] = vx;
      si[base + pos] = ix;
      sm.sort.sval[pos] = vx;
    }
    __syncthreads();
#pragma unroll
    for (int e = 0; e < 4; ++e) {
      const int i2 = tid + e * NTHR;
      const float th = -sl[base + i2];
      int lo = 0, hi = N_;
      while (lo < hi) {
        const int mid = (lo + hi) >> 1;
        if (sm.sort.sval[mid] < th) lo = mid + 1; else hi = mid;
      }
      parr[base + i2] = lo;
    }
#undef BUCKET
  }
  grid.sync();

  // ================= phase 3: chunk prefixes (8 tasks/block) ==============
  {
    const int task = bid * 8 + wave;  // 0..2047
    const int bh = task >> 7;
    const int c = task & 127;
    const int b = bh >> 3, h = bh & 7;
    const int base = bh * N_;
    const int t = c * CH + (lane & 15);
    const float m = sv[base + N_ - 1];
    const float val = sv[base + t];
    const float e1 = __expf(val - m);
    const float e2 = __expf(SLOPE * (val - m));
    const int jv = si[base + t];
    float s1 = e1, s2 = e2;
#pragma unroll
    for (int off = 1; off < 16; off <<= 1) {
      const float o1 = __shfl_up(s1, off, 16);
      const float o2 = __shfl_up(s2, off, 16);
      if ((lane & 15) >= off) { s1 += o1; s2 += o2; }
    }
    if (lane < 16) {
      Zpe1[base + t] = s1 - e1;
      Zpe2[base + t] = s2 - e2;
    }
    if (lane == 15) { Zc1[task] = s1; Zc2[task] = s2; }
    float acc1 = 0.f, acc2 = 0.f;
#pragma unroll
    for (int u = 0; u < CH; ++u) {
      P1[(base + c * CH + u) * 64 + lane] = acc1;
      P2[(base + c * CH + u) * 64 + lane] = acc2;
      const float wa = __shfl(e1, u, 64);
      const float wb = __shfl(e2, u, 64);
      const int j = __shfl(jv, u, 64);
      const float gv = g[(b * N_ + j) * HD + h * DH + lane];
      acc1 = fmaf(wa, gv, acc1);
      acc2 = fmaf(wb, gv, acc2);
    }
    C1[task * 64 + lane] = acc1;
    C2[task * 64 + lane] = acc2;
  }
  grid.sync();

  // ================= phase 4: chunk-sum scan (bid<16) =====================
  if (bid < 16 && tid < 64) {
    const int bh = bid;
    const int d = tid;
    float r1 = 0.f, r2 = 0.f;
#pragma unroll 8
    for (int c = 0; c < NCHUNK; ++c) {
      U1[(bh * 129 + c) * 64 + d] = r1;
      U2[(bh * 129 + c) * 64 + d] = r2;
      r1 += C1[(bh * NCHUNK + c) * 64 + d];
      r2 += C2[(bh * NCHUNK + c) * 64 + d];
    }
    U1[(bh * 129 + NCHUNK) * 64 + d] = r1;
    U2[(bh * 129 + NCHUNK) * 64 + d] = r2;
    if (d == 0) {
      float z1 = 0.f, z2 = 0.f;
#pragma unroll 8
      for (int c = 0; c < NCHUNK; ++c) {
        Zb1[bh * 129 + c] = z1;
        Zb2[bh * 129 + c] = z2;
        z1 += Zc1[bh * NCHUNK + c];
        z2 += Zc2[bh * NCHUNK + c];
      }
      Zb1[bh * 129 + NCHUNK] = z1;
      Zb2[bh * 129 + NCHUNK] = z2;
    }
  }
  grid.sync();

  // ================= phase 5: output combine (16 rows/wave) ===============
  {
    const int d = lane;
    const int wgid = bid * 8 + wave;  // 0..2047
    for (int t = 0; t < 16; ++t) {
      const int wv = wgid * 16 + t;  // 0..32767
      const int h = wv & 7;
      const int row = wv >> 3;
      const int b = row >> 11;
      const int i = row & (N_ - 1);
      const int bh = b * H_ + h;
      const int base = bh * N_;
      const float sli = sl[base + i];
      const float m = sv[base + N_ - 1];
      const int p = parr[base + i];
      const float slm = sli + m;
      const float M = slm >= 0.f ? slm : SLOPE * slm;
      const float c1 = __expf(slm - M);
      const float c2 = __expf(SLOPE * slm - M);
      const int c = p >> 4;
      const float tot1 = U1[(bh * 129 + NCHUNK) * 64 + d];
      const float b1 = U1[(bh * 129 + c) * 64 + d];
      const float b2 = U2[(bh * 129 + c) * 64 + d];
      const float zt1 = Zb1[bh * 129 + NCHUNK];
      const float zb1 = Zb1[bh * 129 + c];
      const float zb2 = Zb2[bh * 129 + c];
      float p1 = 0.f, p2 = 0.f, zp1 = 0.f, zp2 = 0.f;
      if (p < N_) {
        p1 = P1[(base + p) * 64 + d];
        p2 = P2[(base + p) * 64 + d];
        zp1 = Zpe1[base + p];
        zp2 = Zpe2[base + p];
      }
      const float S1 = tot1 - b1 - p1;
      const float P2v = b2 + p2;
      const float Z = c1 * (zt1 - zb1 - zp1) + c2 * (zb2 + zp2);
      out[row * HD + h * DH + d] = (c1 * S1 + c2 * P2v) / Z;
    }
  }
}

extern "C" void kernel_launch(void* const* d_in, const int* in_sizes, int n_in,
                              void* d_out, int out_size, void* d_ws, size_t ws_size,
                              hipStream_t stream) {
  const float* f = (const float*)d_in[0];
  // d_in[1] = adj_mat (all ones, unused by reference math)
  const float* W = (const float*)d_in[2];
  const float* aw = (const float*)d_in[3];
  float* ws = (float*)d_ws;
  float* out = (float*)d_out;
  void* args[] = {(void*)&f, (void*)&W, (void*)&aw, (void*)&ws, (void*)&out};
  hipLaunchCooperativeKernel(reinterpret_cast<void*>(k_mega), dim3(NBLK),
                             dim3(NTHR), args, 0, stream);
}

// Round 11
// 123.128 us; speedup vs baseline: 2.1881x; 2.1881x over previous
//
#include <hip/hip_runtime.h>
#include <hip/hip_bf16.h>

#define B_ 2
#define N_ 2048
#define FIN 512
#define H_ 8
#define DH 64
#define HD 512 /* H_*DH */
#define SLOPE 0.2f
#define NCHUNK 128
#define CH 16

typedef __attribute__((ext_vector_type(8))) short short8;
typedef __attribute__((ext_vector_type(4))) float f32x4;
typedef unsigned short ushort_t;

__device__ __forceinline__ ushort_t hi_trunc(float x) {
  return (ushort_t)(__float_as_uint(x) >> 16);
}
__device__ __forceinline__ ushort_t lo_part(float x) {
  const float hf = __uint_as_float(__float_as_uint(x) & 0xFFFF0000u);
  const __hip_bfloat16 lb = __float2bfloat16(x - hf);
  return *(const ushort_t*)&lb;
}

// K1: g = f @ W via bf16 MFMA split precision (ah*bh + ah*bl + al*bh).
// fp32->bf16 hi/lo conversion fused into staging (regs -> swizzled ds_write).
// BM=128, BN=64, BK=64, 512 thr (8 waves), dbuf, T14 load-early/write-late.
// Fused sl/sr epilogue (col tile == head). Grid (32, 8).
__global__ __launch_bounds__(512) void k_gemm_fused(
    const float* __restrict__ f, const float* __restrict__ W,
    const float* __restrict__ aw, float* __restrict__ C,
    float* __restrict__ sl, float* __restrict__ sr) {
  __shared__ ushort_t lA[2][2][128 * 64];  // [buf][hi/lo] 64KB
  __shared__ ushort_t lB[2][2][64 * 64];   // 32KB
  __shared__ float slp[2][128], srp[2][128];
  const int tid = threadIdx.x;
  const int lane = tid & 63;
  const int wave = tid >> 6;
  const int row0 = blockIdx.x * 128;
  const int col0 = blockIdx.y * 64;
  const int wm = (wave >> 1) * 32;
  const int wn = (wave & 1) * 32;
  // staging coordinates
  const int ar = tid >> 2;             // A row 0..127
  const int aks = (tid & 3) * 16;      // A k-segment (elements)
  const int bn = tid & 63;             // B col (n) == lane -> coalesced
  const int bks = (tid >> 6) * 8;      // B k-segment (8 elements per wave)
  f32x4 acc[2][2] = {};
  float fa[16];
  float fb[8];

#define LOADR(k0)                                                           \
  {                                                                         \
    const float* ap = f + (row0 + ar) * FIN + (k0) + aks;                   \
    _Pragma("unroll") for (int i = 0; i < 4; ++i) {                         \
      const float4 v = *(const float4*)(ap + i * 4);                        \
      fa[i * 4 + 0] = v.x; fa[i * 4 + 1] = v.y;                             \
      fa[i * 4 + 2] = v.z; fa[i * 4 + 3] = v.w;                             \
    }                                                                       \
    _Pragma("unroll") for (int j = 0; j < 8; ++j)                           \
      fb[j] = W[((k0) + bks + j) * HD + col0 + bn];                         \
  }

#define WRITELDS(buf)                                                       \
  {                                                                         \
    _Pragma("unroll") for (int c = 0; c < 2; ++c) {                         \
      short8 hv, lv;                                                        \
      _Pragma("unroll") for (int j = 0; j < 8; ++j) {                       \
        hv[j] = (short)hi_trunc(fa[c * 8 + j]);                             \
        lv[j] = (short)lo_part(fa[c * 8 + j]);                              \
      }                                                                     \
      const int kbA = ((tid & 3) << 5) + (c << 4);                          \
      const int offA = (ar * 128 + (kbA ^ ((ar & 7) << 4))) >> 1;           \
      *(short8*)&lA[buf][0][offA] = hv;                                     \
      *(short8*)&lA[buf][1][offA] = lv;                                     \
    }                                                                       \
    {                                                                       \
      short8 hv, lv;                                                        \
      _Pragma("unroll") for (int j = 0; j < 8; ++j) {                       \
        hv[j] = (short)hi_trunc(fb[j]);                                     \
        lv[j] = (short)lo_part(fb[j]);                                      \
      }                                                                     \
      const int kbB = bks << 1;                                             \
      const int offB = (bn * 128 + (kbB ^ ((bn & 7) << 4))) >> 1;           \
      *(short8*)&lB[buf][0][offB] = hv;                                     \
      *(short8*)&lB[buf][1][offB] = lv;                                     \
    }                                                                       \
  }

  LOADR(0);
  WRITELDS(0);
  __syncthreads();
  int cur = 0;
  for (int t = 0; t < 8; ++t) {
    if (t < 7) LOADR((t + 1) * 64);  // issue next-tile global loads early
#pragma unroll
    for (int kk = 0; kk < 2; ++kk) {
      short8 a_h[2], a_l[2], b_h[2], b_l[2];
      const int kbyte = kk * 64 + ((lane >> 4) << 4);
#pragma unroll
      for (int fm = 0; fm < 2; ++fm) {
        const int row = wm + fm * 16 + (lane & 15);
        const int off = (row * 128 + (kbyte ^ ((row & 7) << 4))) >> 1;
        a_h[fm] = *(const short8*)&lA[cur][0][off];
        a_l[fm] = *(const short8*)&lA[cur][1][off];
      }
#pragma unroll
      for (int fn = 0; fn < 2; ++fn) {
        const int nn = wn + fn * 16 + (lane & 15);
        const int off = (nn * 128 + (kbyte ^ ((nn & 7) << 4))) >> 1;
        b_h[fn] = *(const short8*)&lB[cur][0][off];
        b_l[fn] = *(const short8*)&lB[cur][1][off];
      }
#pragma unroll
      for (int fm = 0; fm < 2; ++fm)
#pragma unroll
        for (int fn = 0; fn < 2; ++fn) {
          acc[fm][fn] = __builtin_amdgcn_mfma_f32_16x16x32_bf16(
              a_h[fm], b_h[fn], acc[fm][fn], 0, 0, 0);
          acc[fm][fn] = __builtin_amdgcn_mfma_f32_16x16x32_bf16(
              a_h[fm], b_l[fn], acc[fm][fn], 0, 0, 0);
          acc[fm][fn] = __builtin_amdgcn_mfma_f32_16x16x32_bf16(
              a_l[fm], b_h[fn], acc[fm][fn], 0, 0, 0);
        }
    }
    if (t < 7) WRITELDS(cur ^ 1);  // write next tile into the other buffer
    __syncthreads();
    cur ^= 1;
  }
#undef LOADR
#undef WRITELDS

  // C-store
#pragma unroll
  for (int fm = 0; fm < 2; ++fm)
#pragma unroll
    for (int fn = 0; fn < 2; ++fn)
#pragma unroll
      for (int r = 0; r < 4; ++r) {
        const int row = row0 + wm + fm * 16 + ((lane >> 4) << 2) + r;
        const int col = col0 + wn + fn * 16 + (lane & 15);
        C[row * HD + col] = acc[fm][fn][r];
      }

  // fused sl/sr epilogue
  const float al0 = aw[wn + (lane & 15)];
  const float al1 = aw[wn + 16 + (lane & 15)];
  const float ar0 = aw[DH + wn + (lane & 15)];
  const float ar1 = aw[DH + wn + 16 + (lane & 15)];
#pragma unroll
  for (int fm = 0; fm < 2; ++fm)
#pragma unroll
    for (int r = 0; r < 4; ++r) {
      float vsl = acc[fm][0][r] * al0 + acc[fm][1][r] * al1;
      float vsr = acc[fm][0][r] * ar0 + acc[fm][1][r] * ar1;
#pragma unroll
      for (int off = 1; off < 16; off <<= 1) {
        vsl += __shfl_xor(vsl, off, 64);
        vsr += __shfl_xor(vsr, off, 64);
      }
      if ((lane & 15) == 0) {
        const int rr = wm + fm * 16 + ((lane >> 4) << 2) + r;
        slp[wn >> 5][rr] = vsl;
        srp[wn >> 5][rr] = vsr;
      }
    }
  __syncthreads();
  if (tid < 128) {
    const int grow = row0 + tid;
    const int b = grow >> 11, n = grow & (N_ - 1);
    const int h = blockIdx.y;
    sl[(b * H_ + h) * N_ + n] = slp[0][tid] + slp[1][tid];
    sr[(b * H_ + h) * N_ + n] = srp[0][tid] + srp[1][tid];
  }
}

// K2: counting sort per (b,h) + fused split search (value-linear buckets).
// Also zeroes the per-bh chunk counters (safe: strictly precedes k_chunks).
__global__ __launch_bounds__(1024) void k_csort(const float* __restrict__ sr,
                                                const float* __restrict__ sl,
                                                float* __restrict__ sv,
                                                int* __restrict__ si,
                                                int* __restrict__ parr,
                                                int* __restrict__ ccnt) {
  __shared__ int hist[N_];
  __shared__ int sbase[N_];
  __shared__ int cursor[N_];
  __shared__ float tsv[N_];
  __shared__ int tsi[N_];
  __shared__ float sval[N_];
  __shared__ float redmn[16], redmx[16];
  __shared__ int wtot[16], wexc[16];
  const int base = blockIdx.x * N_;
  const int tid = threadIdx.x;
  const int lane = tid & 63;
  const int wv = tid >> 6;
  if (tid == 0) ccnt[blockIdx.x] = 0;

  const float v0 = sr[base + tid];
  const float v1 = sr[base + tid + 1024];
  hist[tid] = 0;
  hist[tid + 1024] = 0;
  float mn = fminf(v0, v1);
  float mx = fmaxf(v0, v1);
#pragma unroll
  for (int off = 32; off > 0; off >>= 1) {
    mn = fminf(mn, __shfl_xor(mn, off, 64));
    mx = fmaxf(mx, __shfl_xor(mx, off, 64));
  }
  if (lane == 0) { redmn[wv] = mn; redmx[wv] = mx; }
  __syncthreads();
  if (tid == 0) {
    float m1 = redmn[0], m2 = redmx[0];
#pragma unroll
    for (int w = 1; w < 16; ++w) {
      m1 = fminf(m1, redmn[w]);
      m2 = fmaxf(m2, redmx[w]);
    }
    redmn[0] = m1; redmx[0] = m2;
  }
  __syncthreads();
  const float vmin = redmn[0];
  const float range = redmx[0] - vmin;
  const float scalef = range > 0.f ? 2047.0f / range : 0.0f;
#define BUCKET(v)                                                            \
  ({ int b_ = (int)(((v) - vmin) * scalef); b_ > 2047 ? 2047 : b_; })
  atomicAdd(&hist[BUCKET(v0)], 1);
  atomicAdd(&hist[BUCKET(v1)], 1);
  __syncthreads();
  {
    const int e0 = hist[wv * 128 + lane];
    const int e1 = hist[wv * 128 + 64 + lane];
    int s0 = e0, s1 = e1;
#pragma unroll
    for (int off = 1; off < 64; off <<= 1) {
      const int o0 = __shfl_up(s0, off, 64);
      const int o1 = __shfl_up(s1, off, 64);
      if (lane >= off) { s0 += o0; s1 += o1; }
    }
    const int tot0 = __shfl(s0, 63, 64);
    s1 += tot0;
    sbase[wv * 128 + lane] = s0 - e0;
    sbase[wv * 128 + 64 + lane] = s1 - e1;
    if (lane == 63) wtot[wv] = s1;
  }
  __syncthreads();
  if (tid == 0) {
    int r = 0;
#pragma unroll
    for (int w = 0; w < 16; ++w) { wexc[w] = r; r += wtot[w]; }
  }
  __syncthreads();
  {
    const int a0 = sbase[tid] + wexc[tid >> 7];
    const int a1 = sbase[tid + 1024] + wexc[(tid + 1024) >> 7];
    sbase[tid] = a0;
    sbase[tid + 1024] = a1;
    cursor[tid] = a0;
    cursor[tid + 1024] = a1;
  }
  __syncthreads();
  {
    const int b0 = BUCKET(v0);
    const int p0 = atomicAdd(&cursor[b0], 1);
    tsv[p0] = v0; tsi[p0] = tid;
    const int b1 = BUCKET(v1);
    const int p1 = atomicAdd(&cursor[b1], 1);
    tsv[p1] = v1; tsi[p1] = tid + 1024;
  }
  __syncthreads();
#pragma unroll
  for (int e = 0; e < 2; ++e) {
    const int s = tid + e * 1024;
    const float v = tsv[s];
    const int i = tsi[s];
    const int b = BUCKET(v);
    const int lo = sbase[b];
    const int cnt = hist[b];
    int r = 0;
    for (int t2 = lo; t2 < lo + cnt; ++t2) {
      const float vt = tsv[t2];
      r += (vt < v || (vt == v && tsi[t2] < i)) ? 1 : 0;
    }
    const int pos = lo + r;
    sv[base + pos] = v;
    si[base + pos] = i;
    sval[pos] = v;
  }
  __syncthreads();
#pragma unroll
  for (int e = 0; e < 2; ++e) {
    const int i2 = tid + e * 1024;
    const float th = -sl[base + i2];
    int lo = 0, hi = N_;
    while (lo < hi) {
      const int mid = (lo + hi) >> 1;
      if (sval[mid] < th) lo = mid + 1; else hi = mid;
    }
    parr[base + i2] = lo;
  }
#undef BUCKET
}

// K3: chunk prefixes + (last finisher per bh) the chunk-sum scan.
__global__ __launch_bounds__(64) void k_chunks(const float* __restrict__ g,
                                               const float* __restrict__ sv,
                                               const int* __restrict__ si,
                                               float* __restrict__ P1,
                                               float* __restrict__ P2,
                                               float* __restrict__ Zpe1,
                                               float* __restrict__ Zpe2,
                                               float* __restrict__ C1,
                                               float* __restrict__ C2,
                                               float* __restrict__ Zc1,
                                               float* __restrict__ Zc2,
                                               float* __restrict__ U1,
                                               float* __restrict__ U2,
                                               float* __restrict__ Zb1,
                                               float* __restrict__ Zb2,
                                               int* __restrict__ ccnt) {
  const int bh = blockIdx.x >> 7;
  const int c = blockIdx.x & 127;
  const int b = bh >> 3, h = bh & 7;
  const int lane = threadIdx.x;
  const int base = bh * N_;
  const int t = c * CH + (lane & 15);
  const float m = sv[base + N_ - 1];
  const float val = sv[base + t];
  const float e1 = __expf(val - m);
  const float e2 = __expf(SLOPE * (val - m));
  const int jv = si[base + t];
  float s1 = e1, s2 = e2;
#pragma unroll
  for (int off = 1; off < 16; off <<= 1) {
    const float o1 = __shfl_up(s1, off, 16);
    const float o2 = __shfl_up(s2, off, 16);
    if ((lane & 15) >= off) { s1 += o1; s2 += o2; }
  }
  if (lane < 16) {
    Zpe1[base + t] = s1 - e1;
    Zpe2[base + t] = s2 - e2;
  }
  if (lane == 15) { Zc1[blockIdx.x] = s1; Zc2[blockIdx.x] = s2; }
  float acc1 = 0.f, acc2 = 0.f;
#pragma unroll
  for (int u = 0; u < CH; ++u) {
    P1[(base + c * CH + u) * 64 + lane] = acc1;
    P2[(base + c * CH + u) * 64 + lane] = acc2;
    const float wa = __shfl(e1, u, 64);
    const float wb = __shfl(e2, u, 64);
    const int j = __shfl(jv, u, 64);
    const float gv = g[(b * N_ + j) * HD + h * DH + lane];
    acc1 = fmaf(wa, gv, acc1);
    acc2 = fmaf(wb, gv, acc2);
  }
  C1[blockIdx.x * 64 + lane] = acc1;
  C2[blockIdx.x * 64 + lane] = acc2;

  // last-finisher scan for this bh (release: fence before count; acquire after)
  __threadfence();
  int last = 0;
  if (lane == 0) last = (atomicAdd(&ccnt[bh], 1) == NCHUNK - 1) ? 1 : 0;
  last = __shfl(last, 0, 64);
  if (last) {
    __threadfence();
    const int d = lane;
    float r1 = 0.f, r2 = 0.f;
#pragma unroll 8
    for (int cc = 0; cc < NCHUNK; ++cc) {
      U1[(bh * 129 + cc) * 64 + d] = r1;
      U2[(bh * 129 + cc) * 64 + d] = r2;
      r1 += C1[(bh * NCHUNK + cc) * 64 + d];
      r2 += C2[(bh * NCHUNK + cc) * 64 + d];
    }
    U1[(bh * 129 + NCHUNK) * 64 + d] = r1;
    U2[(bh * 129 + NCHUNK) * 64 + d] = r2;
    if (d == 0) {
      float z1 = 0.f, z2 = 0.f;
#pragma unroll 8
      for (int cc = 0; cc < NCHUNK; ++cc) {
        Zb1[bh * 129 + cc] = z1;
        Zb2[bh * 129 + cc] = z2;
        z1 += Zc1[bh * NCHUNK + cc];
        z2 += Zc2[bh * NCHUNK + cc];
      }
      Zb1[bh * 129 + NCHUNK] = z1;
      Zb2[bh * 129 + NCHUNK] = z2;
    }
  }
}

// K4: branch-free streaming combine using precomputed split p
__global__ __launch_bounds__(256) void k_out(const float* __restrict__ sl,
                                             const float* __restrict__ sv,
                                             const int* __restrict__ parr,
                                             const float* __restrict__ P1,
                                             const float* __restrict__ P2,
                                             const float* __restrict__ Zpe1,
                                             const float* __restrict__ Zpe2,
                                             const float* __restrict__ U1,
                                             const float* __restrict__ U2,
                                             const float* __restrict__ Zb1,
                                             const float* __restrict__ Zb2,
                                             float* __restrict__ out) {
  const int wv = blockIdx.x * 4 + (threadIdx.x >> 6);
  const int d = threadIdx.x & 63;
  const int h = wv & 7;
  const int row = wv >> 3;
  const int b = row >> 11;
  const int i = row & (N_ - 1);
  const int bh = b * H_ + h;
  const int base = bh * N_;
  const float sli = sl[base + i];
  const float m = sv[base + N_ - 1];
  const int p = parr[base + i];
  const float slm = sli + m;
  const float M = slm >= 0.f ? slm : SLOPE * slm;
  const float c1 = __expf(slm - M);
  const float c2 = __expf(SLOPE * slm - M);
  const int c = p >> 4;
  const float tot1 = U1[(bh * 129 + NCHUNK) * 64 + d];
  const float b1 = U1[(bh * 129 + c) * 64 + d];
  const float b2 = U2[(bh * 129 + c) * 64 + d];
  const float zt1 = Zb1[bh * 129 + NCHUNK];
  const float zb1 = Zb1[bh * 129 + c];
  const float zb2 = Zb2[bh * 129 + c];
  float p1 = 0.f, p2 = 0.f, zp1 = 0.f, zp2 = 0.f;
  if (p < N_) {
    p1 = P1[(base + p) * 64 + d];
    p2 = P2[(base + p) * 64 + d];
    zp1 = Zpe1[base + p];
    zp2 = Zpe2[base + p];
  }
  const float S1 = tot1 - b1 - p1;
  const float P2v = b2 + p2;
  const float Z = c1 * (zt1 - zb1 - zp1) + c2 * (zb2 + zp2);
  out[row * HD + h * DH + d] = (c1 * S1 + c2 * P2v) / Z;
}

extern "C" void kernel_launch(void* const* d_in, const int* in_sizes, int n_in,
                              void* d_out, int out_size, void* d_ws, size_t ws_size,
                              hipStream_t stream) {
  const float* f = (const float*)d_in[0];
  // d_in[1] = adj_mat (all ones, unused by reference math)
  const float* W = (const float*)d_in[2];
  const float* aw = (const float*)d_in[3];
  float* out = (float*)d_out;

  float* g = (float*)d_ws;
  float* sl = g + B_ * N_ * HD;
  float* sr = sl + B_ * N_ * H_;
  float* sv = sr + B_ * N_ * H_;
  int* si = (int*)(sv + B_ * N_ * H_);
  float* P1 = (float*)(si + B_ * N_ * H_);
  float* P2 = P1 + B_ * H_ * N_ * 64;
  float* Zpe1 = P2 + B_ * H_ * N_ * 64;
  float* Zpe2 = Zpe1 + B_ * N_ * H_;
  float* U1 = Zpe2 + B_ * N_ * H_;
  float* U2 = U1 + 16 * 129 * 64;
  float* Zb1 = U2 + 16 * 129 * 64;
  float* Zb2 = Zb1 + 16 * 129;
  float* C1 = Zb2 + 16 * 129;
  float* C2 = C1 + 16 * NCHUNK * 64;
  float* Zc1 = C2 + 16 * NCHUNK * 64;
  float* Zc2 = Zc1 + 16 * NCHUNK;
  int* parr = (int*)(Zc2 + 16 * NCHUNK);
  int* ccnt = parr + B_ * N_ * H_;  // 16 per-bh finish counters

  hipLaunchKernelGGL(k_gemm_fused, dim3((B_ * N_) / 128, HD / 64), dim3(512), 0, stream,
                     f, W, aw, g, sl, sr);
  hipLaunchKernelGGL(k_csort, dim3(B_ * H_), dim3(1024), 0, stream, sr, sl, sv, si, parr, ccnt);
  hipLaunchKernelGGL(k_chunks, dim3(B_ * H_ * NCHUNK), dim3(64), 0, stream, g, sv, si,
                     P1, P2, Zpe1, Zpe2, C1, C2, Zc1, Zc2, U1, U2, Zb1, Zb2, ccnt);
  hipLaunchKernelGGL(k_out, dim3(B_ * N_ * H_ / 4), dim3(256), 0, stream,
                     sl, sv, parr, P1, P2, Zpe1, Zpe2, U1, U2, Zb1, Zb2, out);
}

// Round 12
// 47.287 us; speedup vs baseline: 5.6975x; 2.6039x over previous
//
#include <hip/hip_runtime.h>
#include <hip/hip_bf16.h>

#define B_ 2
#define N_ 2048
#define FIN 512
#define H_ 8
#define DH 64
#define HD 512 /* H_*DH */
#define SLOPE 0.2f
#define NCHUNK 128
#define CH 16

typedef __attribute__((ext_vector_type(8))) short short8;
typedef __attribute__((ext_vector_type(4))) float f32x4;
typedef unsigned short ushort_t;

__device__ __forceinline__ ushort_t hi_trunc(float x) {
  return (ushort_t)(__float_as_uint(x) >> 16);
}
__device__ __forceinline__ ushort_t lo_part(float x) {
  const float hf = __uint_as_float(__float_as_uint(x) & 0xFFFF0000u);
  const __hip_bfloat16 lb = __float2bfloat16(x - hf);
  return *(const ushort_t*)&lb;
}

// K1: g = f @ W via bf16 MFMA split precision (ah*bh + ah*bl + al*bh).
// fp32->bf16 hi/lo conversion fused into staging (regs -> swizzled ds_write).
// BM=128, BN=64, BK=64, 512 thr (8 waves), dbuf, load-early/write-late.
// Fused sl/sr epilogue (col tile == head). Grid (32, 8).
__global__ __launch_bounds__(512) void k_gemm_fused(
    const float* __restrict__ f, const float* __restrict__ W,
    const float* __restrict__ aw, float* __restrict__ C,
    float* __restrict__ sl, float* __restrict__ sr) {
  __shared__ ushort_t lA[2][2][128 * 64];  // [buf][hi/lo] 64KB
  __shared__ ushort_t lB[2][2][64 * 64];   // 32KB
  __shared__ float slp[2][128], srp[2][128];
  const int tid = threadIdx.x;
  const int lane = tid & 63;
  const int wave = tid >> 6;
  const int row0 = blockIdx.x * 128;
  const int col0 = blockIdx.y * 64;
  const int wm = (wave >> 1) * 32;
  const int wn = (wave & 1) * 32;
  const int ar = tid >> 2;             // A row 0..127
  const int aks = (tid & 3) * 16;      // A k-segment (elements)
  const int bn = tid & 63;             // B col (n) == lane -> coalesced
  const int bks = (tid >> 6) * 8;      // B k-segment
  f32x4 acc[2][2] = {};
  float fa[16];
  float fb[8];

#define LOADR(k0)                                                           \
  {                                                                         \
    const float* ap = f + (row0 + ar) * FIN + (k0) + aks;                   \
    _Pragma("unroll") for (int i = 0; i < 4; ++i) {                         \
      const float4 v = *(const float4*)(ap + i * 4);                        \
      fa[i * 4 + 0] = v.x; fa[i * 4 + 1] = v.y;                             \
      fa[i * 4 + 2] = v.z; fa[i * 4 + 3] = v.w;                             \
    }                                                                       \
    _Pragma("unroll") for (int j = 0; j < 8; ++j)                           \
      fb[j] = W[((k0) + bks + j) * HD + col0 + bn];                         \
  }

#define WRITELDS(buf)                                                       \
  {                                                                         \
    _Pragma("unroll") for (int c = 0; c < 2; ++c) {                         \
      short8 hv, lv;                                                        \
      _Pragma("unroll") for (int j = 0; j < 8; ++j) {                       \
        hv[j] = (short)hi_trunc(fa[c * 8 + j]);                             \
        lv[j] = (short)lo_part(fa[c * 8 + j]);                              \
      }                                                                     \
      const int kbA = ((tid & 3) << 5) + (c << 4);                          \
      const int offA = (ar * 128 + (kbA ^ ((ar & 7) << 4))) >> 1;           \
      *(short8*)&lA[buf][0][offA] = hv;                                     \
      *(short8*)&lA[buf][1][offA] = lv;                                     \
    }                                                                       \
    {                                                                       \
      short8 hv, lv;                                                        \
      _Pragma("unroll") for (int j = 0; j < 8; ++j) {                       \
        hv[j] = (short)hi_trunc(fb[j]);                                     \
        lv[j] = (short)lo_part(fb[j]);                                      \
      }                                                                     \
      const int kbB = bks << 1;                                             \
      const int offB = (bn * 128 + (kbB ^ ((bn & 7) << 4))) >> 1;           \
      *(short8*)&lB[buf][0][offB] = hv;                                     \
      *(short8*)&lB[buf][1][offB] = lv;                                     \
    }                                                                       \
  }

  LOADR(0);
  WRITELDS(0);
  __syncthreads();
  int cur = 0;
  for (int t = 0; t < 8; ++t) {
    if (t < 7) LOADR((t + 1) * 64);  // issue next-tile global loads early
#pragma unroll
    for (int kk = 0; kk < 2; ++kk) {
      short8 a_h[2], a_l[2], b_h[2], b_l[2];
      const int kbyte = kk * 64 + ((lane >> 4) << 4);
#pragma unroll
      for (int fm = 0; fm < 2; ++fm) {
        const int row = wm + fm * 16 + (lane & 15);
        const int off = (row * 128 + (kbyte ^ ((row & 7) << 4))) >> 1;
        a_h[fm] = *(const short8*)&lA[cur][0][off];
        a_l[fm] = *(const short8*)&lA[cur][1][off];
      }
#pragma unroll
      for (int fn = 0; fn < 2; ++fn) {
        const int nn = wn + fn * 16 + (lane & 15);
        const int off = (nn * 128 + (kbyte ^ ((nn & 7) << 4))) >> 1;
        b_h[fn] = *(const short8*)&lB[cur][0][off];
        b_l[fn] = *(const short8*)&lB[cur][1][off];
      }
#pragma unroll
      for (int fm = 0; fm < 2; ++fm)
#pragma unroll
        for (int fn = 0; fn < 2; ++fn) {
          acc[fm][fn] = __builtin_amdgcn_mfma_f32_16x16x32_bf16(
              a_h[fm], b_h[fn], acc[fm][fn], 0, 0, 0);
          acc[fm][fn] = __builtin_amdgcn_mfma_f32_16x16x32_bf16(
              a_h[fm], b_l[fn], acc[fm][fn], 0, 0, 0);
          acc[fm][fn] = __builtin_amdgcn_mfma_f32_16x16x32_bf16(
              a_l[fm], b_h[fn], acc[fm][fn], 0, 0, 0);
        }
    }
    if (t < 7) WRITELDS(cur ^ 1);
    __syncthreads();
    cur ^= 1;
  }
#undef LOADR
#undef WRITELDS

  // C-store
#pragma unroll
  for (int fm = 0; fm < 2; ++fm)
#pragma unroll
    for (int fn = 0; fn < 2; ++fn)
#pragma unroll
      for (int r = 0; r < 4; ++r) {
        const int row = row0 + wm + fm * 16 + ((lane >> 4) << 2) + r;
        const int col = col0 + wn + fn * 16 + (lane & 15);
        C[row * HD + col] = acc[fm][fn][r];
      }

  // fused sl/sr epilogue
  const float al0 = aw[wn + (lane & 15)];
  const float al1 = aw[wn + 16 + (lane & 15)];
  const float ar0 = aw[DH + wn + (lane & 15)];
  const float ar1 = aw[DH + wn + 16 + (lane & 15)];
#pragma unroll
  for (int fm = 0; fm < 2; ++fm)
#pragma unroll
    for (int r = 0; r < 4; ++r) {
      float vsl = acc[fm][0][r] * al0 + acc[fm][1][r] * al1;
      float vsr = acc[fm][0][r] * ar0 + acc[fm][1][r] * ar1;
#pragma unroll
      for (int off = 1; off < 16; off <<= 1) {
        vsl += __shfl_xor(vsl, off, 64);
        vsr += __shfl_xor(vsr, off, 64);
      }
      if ((lane & 15) == 0) {
        const int rr = wm + fm * 16 + ((lane >> 4) << 2) + r;
        slp[wn >> 5][rr] = vsl;
        srp[wn >> 5][rr] = vsr;
      }
    }
  __syncthreads();
  if (tid < 128) {
    const int grow = row0 + tid;
    const int b = grow >> 11, n = grow & (N_ - 1);
    const int h = blockIdx.y;
    sl[(b * H_ + h) * N_ + n] = slp[0][tid] + slp[1][tid];
    sr[(b * H_ + h) * N_ + n] = srp[0][tid] + srp[1][tid];
  }
}

// K2: counting sort per (b,h) + fused split search (value-linear buckets).
__global__ __launch_bounds__(1024) void k_csort(const float* __restrict__ sr,
                                                const float* __restrict__ sl,
                                                float* __restrict__ sv,
                                                int* __restrict__ si,
                                                int* __restrict__ parr) {
  __shared__ int hist[N_];
  __shared__ int sbase[N_];
  __shared__ int cursor[N_];
  __shared__ float tsv[N_];
  __shared__ int tsi[N_];
  __shared__ float sval[N_];
  __shared__ float redmn[16], redmx[16];
  __shared__ int wtot[16], wexc[16];
  const int base = blockIdx.x * N_;
  const int tid = threadIdx.x;
  const int lane = tid & 63;
  const int wv = tid >> 6;

  const float v0 = sr[base + tid];
  const float v1 = sr[base + tid + 1024];
  hist[tid] = 0;
  hist[tid + 1024] = 0;
  float mn = fminf(v0, v1);
  float mx = fmaxf(v0, v1);
#pragma unroll
  for (int off = 32; off > 0; off >>= 1) {
    mn = fminf(mn, __shfl_xor(mn, off, 64));
    mx = fmaxf(mx, __shfl_xor(mx, off, 64));
  }
  if (lane == 0) { redmn[wv] = mn; redmx[wv] = mx; }
  __syncthreads();
  if (tid == 0) {
    float m1 = redmn[0], m2 = redmx[0];
#pragma unroll
    for (int w = 1; w < 16; ++w) {
      m1 = fminf(m1, redmn[w]);
      m2 = fmaxf(m2, redmx[w]);
    }
    redmn[0] = m1; redmx[0] = m2;
  }
  __syncthreads();
  const float vmin = redmn[0];
  const float range = redmx[0] - vmin;
  const float scalef = range > 0.f ? 2047.0f / range : 0.0f;
#define BUCKET(v)                                                            \
  ({ int b_ = (int)(((v) - vmin) * scalef); b_ > 2047 ? 2047 : b_; })
  atomicAdd(&hist[BUCKET(v0)], 1);
  atomicAdd(&hist[BUCKET(v1)], 1);
  __syncthreads();
  {
    const int e0 = hist[wv * 128 + lane];
    const int e1 = hist[wv * 128 + 64 + lane];
    int s0 = e0, s1 = e1;
#pragma unroll
    for (int off = 1; off < 64; off <<= 1) {
      const int o0 = __shfl_up(s0, off, 64);
      const int o1 = __shfl_up(s1, off, 64);
      if (lane >= off) { s0 += o0; s1 += o1; }
    }
    const int tot0 = __shfl(s0, 63, 64);
    s1 += tot0;
    sbase[wv * 128 + lane] = s0 - e0;
    sbase[wv * 128 + 64 + lane] = s1 - e1;
    if (lane == 63) wtot[wv] = s1;
  }
  __syncthreads();
  if (tid == 0) {
    int r = 0;
#pragma unroll
    for (int w = 0; w < 16; ++w) { wexc[w] = r; r += wtot[w]; }
  }
  __syncthreads();
  {
    const int a0 = sbase[tid] + wexc[tid >> 7];
    const int a1 = sbase[tid + 1024] + wexc[(tid + 1024) >> 7];
    sbase[tid] = a0;
    sbase[tid + 1024] = a1;
    cursor[tid] = a0;
    cursor[tid + 1024] = a1;
  }
  __syncthreads();
  {
    const int b0 = BUCKET(v0);
    const int p0 = atomicAdd(&cursor[b0], 1);
    tsv[p0] = v0; tsi[p0] = tid;
    const int b1 = BUCKET(v1);
    const int p1 = atomicAdd(&cursor[b1], 1);
    tsv[p1] = v1; tsi[p1] = tid + 1024;
  }
  __syncthreads();
#pragma unroll
  for (int e = 0; e < 2; ++e) {
    const int s = tid + e * 1024;
    const float v = tsv[s];
    const int i = tsi[s];
    const int b = BUCKET(v);
    const int lo = sbase[b];
    const int cnt = hist[b];
    int r = 0;
    for (int t2 = lo; t2 < lo + cnt; ++t2) {
      const float vt = tsv[t2];
      r += (vt < v || (vt == v && tsi[t2] < i)) ? 1 : 0;
    }
    const int pos = lo + r;
    sv[base + pos] = v;
    si[base + pos] = i;
    sval[pos] = v;
  }
  __syncthreads();
#pragma unroll
  for (int e = 0; e < 2; ++e) {
    const int i2 = tid + e * 1024;
    const float th = -sl[base + i2];
    int lo = 0, hi = N_;
    while (lo < hi) {
      const int mid = (lo + hi) >> 1;
      if (sval[mid] < th) lo = mid + 1; else hi = mid;
    }
    parr[base + i2] = lo;
  }
#undef BUCKET
}

// K3: chunk prefixes (plain R9 version — no fence, no finisher).
__global__ __launch_bounds__(64) void k_chunks(const float* __restrict__ g,
                                               const float* __restrict__ sv,
                                               const int* __restrict__ si,
                                               float* __restrict__ P1,
                                               float* __restrict__ P2,
                                               float* __restrict__ Zpe1,
                                               float* __restrict__ Zpe2,
                                               float* __restrict__ C1,
                                               float* __restrict__ C2,
                                               float* __restrict__ Zc1,
                                               float* __restrict__ Zc2) {
  const int bh = blockIdx.x >> 7;
  const int c = blockIdx.x & 127;
  const int b = bh >> 3, h = bh & 7;
  const int lane = threadIdx.x;
  const int base = bh * N_;
  const int t = c * CH + (lane & 15);
  const float m = sv[base + N_ - 1];
  const float val = sv[base + t];
  const float e1 = __expf(val - m);
  const float e2 = __expf(SLOPE * (val - m));
  const int jv = si[base + t];
  float s1 = e1, s2 = e2;
#pragma unroll
  for (int off = 1; off < 16; off <<= 1) {
    const float o1 = __shfl_up(s1, off, 16);
    const float o2 = __shfl_up(s2, off, 16);
    if ((lane & 15) >= off) { s1 += o1; s2 += o2; }
  }
  if (lane < 16) {
    Zpe1[base + t] = s1 - e1;
    Zpe2[base + t] = s2 - e2;
  }
  if (lane == 15) { Zc1[blockIdx.x] = s1; Zc2[blockIdx.x] = s2; }
  float acc1 = 0.f, acc2 = 0.f;
#pragma unroll
  for (int u = 0; u < CH; ++u) {
    P1[(base + c * CH + u) * 64 + lane] = acc1;
    P2[(base + c * CH + u) * 64 + lane] = acc2;
    const float wa = __shfl(e1, u, 64);
    const float wb = __shfl(e2, u, 64);
    const int j = __shfl(jv, u, 64);
    const float gv = g[(b * N_ + j) * HD + h * DH + lane];
    acc1 = fmaf(wa, gv, acc1);
    acc2 = fmaf(wb, gv, acc2);
  }
  C1[blockIdx.x * 64 + lane] = acc1;
  C2[blockIdx.x * 64 + lane] = acc2;
}

// K4: parallel scan of chunk sums. 16 blocks x 1024 threads.
// thread (seg,d): seg = tid>>6 (0..15) scans 8 chunks for dim d = tid&63.
// Cross-segment offsets via LDS partial totals. Zb via 128-thread 2-wave scan.
__global__ __launch_bounds__(1024) void k_scan(const float* __restrict__ C1,
                                               const float* __restrict__ C2,
                                               const float* __restrict__ Zc1,
                                               const float* __restrict__ Zc2,
                                               float* __restrict__ U1,
                                               float* __restrict__ U2,
                                               float* __restrict__ Zb1,
                                               float* __restrict__ Zb2) {
  __shared__ float pt1[16][64], pt2[16][64];
  __shared__ float zw[2][2];
  const int bh = blockIdx.x;
  const int tid = threadIdx.x;
  const int d = tid & 63;
  const int seg = tid >> 6;
  float v1[8], v2[8];
  float s1 = 0.f, s2 = 0.f;
#pragma unroll
  for (int k = 0; k < 8; ++k) {
    v1[k] = C1[(bh * NCHUNK + seg * 8 + k) * 64 + d];
    v2[k] = C2[(bh * NCHUNK + seg * 8 + k) * 64 + d];
    s1 += v1[k];
    s2 += v2[k];
  }
  pt1[seg][d] = s1;
  pt2[seg][d] = s2;
  __syncthreads();
  float b1 = 0.f, b2 = 0.f;
  for (int s = 0; s < 16; ++s) {
    if (s < seg) { b1 += pt1[s][d]; b2 += pt2[s][d]; }
  }
#pragma unroll
  for (int k = 0; k < 8; ++k) {
    U1[(bh * 129 + seg * 8 + k) * 64 + d] = b1;
    U2[(bh * 129 + seg * 8 + k) * 64 + d] = b2;
    b1 += v1[k];
    b2 += v2[k];
  }
  if (seg == 15) {
    U1[(bh * 129 + NCHUNK) * 64 + d] = b1;
    U2[(bh * 129 + NCHUNK) * 64 + d] = b2;
  }
  // Zb: 128 threads, 2-wave scan
  if (tid < 128) {
    const int lane = tid & 63;
    const int w = tid >> 6;
    const float z1 = Zc1[bh * NCHUNK + tid];
    const float z2 = Zc2[bh * NCHUNK + tid];
    float a1 = z1, a2 = z2;
#pragma unroll
    for (int off = 1; off < 64; off <<= 1) {
      const float o1 = __shfl_up(a1, off, 64);
      const float o2 = __shfl_up(a2, off, 64);
      if (lane >= off) { a1 += o1; a2 += o2; }
    }
    if (lane == 63) { zw[w][0] = a1; zw[w][1] = a2; }
    __builtin_amdgcn_s_barrier();
    const float add1 = (w == 1) ? zw[0][0] : 0.f;
    const float add2 = (w == 1) ? zw[0][1] : 0.f;
    Zb1[bh * 129 + tid] = a1 - z1 + add1;
    Zb2[bh * 129 + tid] = a2 - z2 + add2;
    if (tid == 127) {
      Zb1[bh * 129 + NCHUNK] = a1 + add1;
      Zb2[bh * 129 + NCHUNK] = a2 + add2;
    }
  }
}

// K5: branch-free streaming combine using precomputed split p
__global__ __launch_bounds__(256) void k_out(const float* __restrict__ sl,
                                             const float* __restrict__ sv,
                                             const int* __restrict__ parr,
                                             const float* __restrict__ P1,
                                             const float* __restrict__ P2,
                                             const float* __restrict__ Zpe1,
                                             const float* __restrict__ Zpe2,
                                             const float* __restrict__ U1,
                                             const float* __restrict__ U2,
                                             const float* __restrict__ Zb1,
                                             const float* __restrict__ Zb2,
                                             float* __restrict__ out) {
  const int wv = blockIdx.x * 4 + (threadIdx.x >> 6);
  const int d = threadIdx.x & 63;
  const int h = wv & 7;
  const int row = wv >> 3;
  const int b = row >> 11;
  const int i = row & (N_ - 1);
  const int bh = b * H_ + h;
  const int base = bh * N_;
  const float sli = sl[base + i];
  const float m = sv[base + N_ - 1];
  const int p = parr[base + i];
  const float slm = sli + m;
  const float M = slm >= 0.f ? slm : SLOPE * slm;
  const float c1 = __expf(slm - M);
  const float c2 = __expf(SLOPE * slm - M);
  const int c = p >> 4;
  const float tot1 = U1[(bh * 129 + NCHUNK) * 64 + d];
  const float b1 = U1[(bh * 129 + c) * 64 + d];
  const float b2 = U2[(bh * 129 + c) * 64 + d];
  const float zt1 = Zb1[bh * 129 + NCHUNK];
  const float zb1 = Zb1[bh * 129 + c];
  const float zb2 = Zb2[bh * 129 + c];
  float p1 = 0.f, p2 = 0.f, zp1 = 0.f, zp2 = 0.f;
  if (p < N_) {
    p1 = P1[(base + p) * 64 + d];
    p2 = P2[(base + p) * 64 + d];
    zp1 = Zpe1[base + p];
    zp2 = Zpe2[base + p];
  }
  const float S1 = tot1 - b1 - p1;
  const float P2v = b2 + p2;
  const float Z = c1 * (zt1 - zb1 - zp1) + c2 * (zb2 + zp2);
  out[row * HD + h * DH + d] = (c1 * S1 + c2 * P2v) / Z;
}

extern "C" void kernel_launch(void* const* d_in, const int* in_sizes, int n_in,
                              void* d_out, int out_size, void* d_ws, size_t ws_size,
                              hipStream_t stream) {
  const float* f = (const float*)d_in[0];
  // d_in[1] = adj_mat (all ones, unused by reference math)
  const float* W = (const float*)d_in[2];
  const float* aw = (const float*)d_in[3];
  float* out = (float*)d_out;

  float* g = (float*)d_ws;
  float* sl = g + B_ * N_ * HD;
  float* sr = sl + B_ * N_ * H_;
  float* sv = sr + B_ * N_ * H_;
  int* si = (int*)(sv + B_ * N_ * H_);
  float* P1 = (float*)(si + B_ * N_ * H_);
  float* P2 = P1 + B_ * H_ * N_ * 64;
  float* Zpe1 = P2 + B_ * H_ * N_ * 64;
  float* Zpe2 = Zpe1 + B_ * N_ * H_;
  float* U1 = Zpe2 + B_ * N_ * H_;
  float* U2 = U1 + 16 * 129 * 64;
  float* Zb1 = U2 + 16 * 129 * 64;
  float* Zb2 = Zb1 + 16 * 129;
  float* C1 = Zb2 + 16 * 129;
  float* C2 = C1 + 16 * NCHUNK * 64;
  float* Zc1 = C2 + 16 * NCHUNK * 64;
  float* Zc2 = Zc1 + 16 * NCHUNK;
  int* parr = (int*)(Zc2 + 16 * NCHUNK);

  hipLaunchKernelGGL(k_gemm_fused, dim3((B_ * N_) / 128, HD / 64), dim3(512), 0, stream,
                     f, W, aw, g, sl, sr);
  hipLaunchKernelGGL(k_csort, dim3(B_ * H_), dim3(1024), 0, stream, sr, sl, sv, si, parr);
  hipLaunchKernelGGL(k_chunks, dim3(B_ * H_ * NCHUNK), dim3(64), 0, stream, g, sv, si,
                     P1, P2, Zpe1, Zpe2, C1, C2, Zc1, Zc2);
  hipLaunchKernelGGL(k_scan, dim3(B_ * H_), dim3(1024), 0, stream, C1, C2, Zc1, Zc2,
                     U1, U2, Zb1, Zb2);
  hipLaunchKernelGGL(k_out, dim3(B_ * N_ * H_ / 4), dim3(256), 0, stream,
                     sl, sv, parr, P1, P2, Zpe1, Zpe2, U1, U2, Zb1, Zb2, out);
}